// Round 1
// baseline (1749.319 us; speedup 1.0000x reference)
//
#include <hip/hip_runtime.h>
#include <math.h>

#define NTOKEN 50257
#define NROWS  2240
#define DDIM   400
#define ALPHA_ 0.2f
#define EPS_   1e-8f

#define BM 128
#define BN 128
#define BK 16
#define NCB ((NTOKEN + BN - 1) / BN)   /* 393 col blocks */
#define NRB ((NROWS  + BM - 1) / BM)   /* 18 row blocks  */

// ---------- wave (64-lane) reductions ----------
__device__ __forceinline__ float wred_sum(float v) {
#pragma unroll
  for (int o = 32; o > 0; o >>= 1) v += __shfl_down(v, o, 64);
  return v;
}

// ---------- kernel 1: per-row stats + representative (last-write-wins) ----------
// coef[i] = -ALPHA * n_w * 1[cos>0] / n_output  (so noise_rows[i] = coef[i]*h[i])
// rep[t]  = max row index with target t  (last-write wins on duplicate targets)
__global__ void row_stats_k(const float* __restrict__ x,
                            const float* __restrict__ enc_w,
                            const int* __restrict__ tgt,
                            float* __restrict__ coef,
                            int* __restrict__ rep) {
  const int i = blockIdx.x;
  const int lane = threadIdx.x;           // 64 threads = 1 wave
  const int t = tgt[i];
  const float* h = x + (size_t)i * DDIM;
  const float* w = enc_w + (size_t)t * DDIM;
  float hh = 0.f, hw = 0.f, ww = 0.f;
  for (int c = lane; c < DDIM; c += 64) {
    float a = h[c], b = w[c];
    hh += a * a; hw += a * b; ww += b * b;
  }
  hh = wred_sum(hh); hw = wred_sum(hw); ww = wred_sum(ww);
  if (lane == 0) {
    float n_out = sqrtf(hh + EPS_);
    float n_w   = sqrtf(ww + EPS_);
    // cos_theta > 0  <=>  hw > 0 (norms strictly positive)
    coef[i] = (hw > 0.f) ? (-ALPHA_ * n_w / n_out) : 0.f;
    atomicMax(rep + t, i);
  }
}

// ---------- kernel 2: noise_outputs[i] = coef[rep[t_i]] * dot(h_i, h_rep) ----------
__global__ void noise_out_k(const float* __restrict__ x,
                            const int* __restrict__ tgt,
                            const int* __restrict__ rep,
                            const float* __restrict__ coef,
                            float* __restrict__ nout) {
  const int i = blockIdx.x;
  const int lane = threadIdx.x;           // 64 threads
  const int j = rep[tgt[i]];              // representative row (>=0 always)
  const float* hi = x + (size_t)i * DDIM;
  const float* hj = x + (size_t)j * DDIM;
  float s = 0.f;
  for (int c = lane; c < DDIM; c += 64) s += hi[c] * hj[c];
  s = wred_sum(s);
  if (lane == 0) nout[i] = coef[j] * s;
}

// ---------- kernel 3: fused GEMM (+bias +noise@target) -> raw logits + softmax partials ----------
// C[r][c] = h[r] . dec_w[c] + dec_b[c] + (c==tgt[r] ? nout[r] : 0)
// also per (row, colblock): pmax = max_c C, psum = sum_c exp(C - pmax)
__global__ __launch_bounds__(256, 2)
void gemm_logits_k(const float* __restrict__ x,
                   const float* __restrict__ w,
                   const float* __restrict__ bias,
                   const int* __restrict__ tgt,
                   const float* __restrict__ nout,
                   float* __restrict__ out,
                   float* __restrict__ pmax,
                   float* __restrict__ psum) {
  __shared__ float As[BK][BM];
  __shared__ float Bs[BK][BN];
  const int bm0 = blockIdx.y * BM;
  const int bn0 = blockIdx.x * BN;
  const int tid = threadIdx.x;
  const int tm = tid >> 4;                // 0..15
  const int tn = tid & 15;                // 0..15
  const int lr = tid >> 1;                // 0..127 (staging row within tile)
  const int lk = (tid & 1) << 3;          // 0 or 8 (staging k within tile)

  const int arow = bm0 + lr;
  const int brow = bn0 + lr;
  const bool aval = (arow < NROWS);
  const bool bval = (brow < NTOKEN);
  const float* aptr = x + (size_t)arow * DDIM + lk;
  const float* bptr = w + (size_t)brow * DDIM + lk;

  float acc[8][8];
#pragma unroll
  for (int i = 0; i < 8; ++i)
#pragma unroll
    for (int j = 0; j < 8; ++j) acc[i][j] = 0.f;

  for (int k0 = 0; k0 < DDIM; k0 += BK) {
    float4 a0 = {0,0,0,0}, a1 = {0,0,0,0}, b0 = {0,0,0,0}, b1 = {0,0,0,0};
    if (aval) { a0 = *(const float4*)(aptr + k0); a1 = *(const float4*)(aptr + k0 + 4); }
    if (bval) { b0 = *(const float4*)(bptr + k0); b1 = *(const float4*)(bptr + k0 + 4); }
    __syncthreads();   // previous iteration's LDS reads complete
    As[lk+0][lr] = a0.x; As[lk+1][lr] = a0.y; As[lk+2][lr] = a0.z; As[lk+3][lr] = a0.w;
    As[lk+4][lr] = a1.x; As[lk+5][lr] = a1.y; As[lk+6][lr] = a1.z; As[lk+7][lr] = a1.w;
    Bs[lk+0][lr] = b0.x; Bs[lk+1][lr] = b0.y; Bs[lk+2][lr] = b0.z; Bs[lk+3][lr] = b0.w;
    Bs[lk+4][lr] = b1.x; Bs[lk+5][lr] = b1.y; Bs[lk+6][lr] = b1.z; Bs[lk+7][lr] = b1.w;
    __syncthreads();
#pragma unroll
    for (int k = 0; k < BK; ++k) {
      const float4 av0 = *(const float4*)&As[k][tm * 8];
      const float4 av1 = *(const float4*)&As[k][tm * 8 + 4];
      const float4 bv0 = *(const float4*)&Bs[k][tn * 8];
      const float4 bv1 = *(const float4*)&Bs[k][tn * 8 + 4];
      const float a[8] = {av0.x, av0.y, av0.z, av0.w, av1.x, av1.y, av1.z, av1.w};
      const float b[8] = {bv0.x, bv0.y, bv0.z, bv0.w, bv1.x, bv1.y, bv1.z, bv1.w};
#pragma unroll
      for (int i = 0; i < 8; ++i)
#pragma unroll
        for (int j = 0; j < 8; ++j) acc[i][j] = fmaf(a[i], b[j], acc[i][j]);
    }
  }

  // ---- epilogue: bias + noise, store raw logits, per-row partial (max, sumexp) ----
  const int r0 = bm0 + tm * 8;
  const int c0 = bn0 + tn * 8;
  float bj[8];
#pragma unroll
  for (int j = 0; j < 8; ++j) {
    const int c = c0 + j;
    bj[j] = (c < NTOKEN) ? bias[c] : 0.f;
  }
  float rmax[8], rsum[8];
#pragma unroll
  for (int i = 0; i < 8; ++i) {
    rmax[i] = -INFINITY; rsum[i] = 0.f;
    const int r = r0 + i;
    if (r < NROWS) {
      const int   tr = tgt[r];
      const float nz = nout[r];
      float vv[8];
#pragma unroll
      for (int j = 0; j < 8; ++j) {
        const int c = c0 + j;
        float v = acc[i][j] + bj[j];
        if (c == tr) v += nz;
        vv[j] = v;
        if (c < NTOKEN) rmax[i] = fmaxf(rmax[i], v);
      }
      float* orow = out + (size_t)r * NTOKEN + c0;
#pragma unroll
      for (int j = 0; j < 8; ++j) if (c0 + j < NTOKEN) orow[j] = vv[j];
#pragma unroll
      for (int j = 0; j < 8; ++j) if (c0 + j < NTOKEN) rsum[i] += expf(vv[j] - rmax[i]);
    }
  }

  // ---- block-level reduce of (max,sum) across the 16 tn columns, per row ----
  __syncthreads();
  float* redm = &As[0][0];   // 2048 floats (128 rows x 16)
  float* reds = &Bs[0][0];
#pragma unroll
  for (int i = 0; i < 8; ++i) {
    redm[(tm * 8 + i) * 16 + tn] = rmax[i];
    reds[(tm * 8 + i) * 16 + tn] = rsum[i];
  }
  __syncthreads();
  if (tid < 128) {
    const int r = bm0 + tid;
    if (r < NROWS) {
      float M = -INFINITY;
#pragma unroll
      for (int u = 0; u < 16; ++u) M = fmaxf(M, redm[tid * 16 + u]);
      float S = 0.f;
#pragma unroll
      for (int u = 0; u < 16; ++u) {
        const float s = reds[tid * 16 + u];
        if (s > 0.f) S += s * expf(redm[tid * 16 + u] - M);
      }
      pmax[(size_t)r * NCB + blockIdx.x] = M;
      psum[(size_t)r * NCB + blockIdx.x] = S;
    }
  }
}

// ---------- kernel 4: combine per-row partials -> roff[r] = M + log(S) ----------
__global__ void combine_k(const float* __restrict__ pmax,
                          const float* __restrict__ psum,
                          float* __restrict__ roff) {
  const int r = blockIdx.x;
  const int lane = threadIdx.x;           // 64 threads
  float M = -INFINITY, S = 0.f;
  for (int u = lane; u < NCB; u += 64) {
    const float m = pmax[(size_t)r * NCB + u];
    const float s = psum[(size_t)r * NCB + u];
    const float nm = fmaxf(M, m);
    S = S * expf(M - nm) + s * expf(m - nm);
    M = nm;
  }
#pragma unroll
  for (int o = 32; o > 0; o >>= 1) {
    const float m2 = __shfl_down(M, o, 64);
    const float s2 = __shfl_down(S, o, 64);
    const float nm = fmaxf(M, m2);
    S = S * expf(M - nm) + s2 * expf(m2 - nm);
    M = nm;
  }
  if (lane == 0) roff[r] = M + logf(S);
}

// ---------- kernel 5: normalize: out[r][c] -= roff[r] ----------
__global__ void normalize_k(float* __restrict__ out,
                            const float* __restrict__ roff,
                            int total4) {
  const int idx = blockIdx.x * blockDim.x + threadIdx.x;
  if (idx >= total4) return;
  float4 v = ((float4*)out)[idx];
  const int base = idx * 4;
  v.x -= roff[(base + 0) / NTOKEN];
  v.y -= roff[(base + 1) / NTOKEN];
  v.z -= roff[(base + 2) / NTOKEN];
  v.w -= roff[(base + 3) / NTOKEN];
  ((float4*)out)[idx] = v;
}

extern "C" void kernel_launch(void* const* d_in, const int* in_sizes, int n_in,
                              void* d_out, int out_size, void* d_ws, size_t ws_size,
                              hipStream_t stream) {
  const float* x     = (const float*)d_in[0];   // (2240, 400) flattened
  const float* dec_w = (const float*)d_in[1];   // (50257, 400)
  const float* dec_b = (const float*)d_in[2];   // (50257,)
  const float* enc_w = (const float*)d_in[3];   // (50257, 400)
  const int*   tgt   = (const int*)d_in[4];     // (2240,)
  float* out = (float*)d_out;                   // (2240, 50257)

  char* ws = (char*)d_ws;
  size_t off = 0;
  auto take = [&](size_t bytes) -> char* {
    char* p = ws + off;
    off = (off + bytes + 255) & ~(size_t)255;
    return p;
  };
  int*   rep  = (int*)  take((size_t)NTOKEN * sizeof(int));
  float* coef = (float*)take((size_t)NROWS * sizeof(float));
  float* nout = (float*)take((size_t)NROWS * sizeof(float));
  float* roff = (float*)take((size_t)NROWS * sizeof(float));
  float* pmax = (float*)take((size_t)NROWS * NCB * sizeof(float));
  float* psum = (float*)take((size_t)NROWS * NCB * sizeof(float));
  (void)ws_size; (void)in_sizes; (void)n_in; (void)out_size;

  // rep = -1 everywhere (0xFF bytes); ws is re-poisoned before every call
  hipMemsetAsync(rep, 0xFF, (size_t)NTOKEN * sizeof(int), stream);

  row_stats_k<<<NROWS, 64, 0, stream>>>(x, enc_w, tgt, coef, rep);
  noise_out_k<<<NROWS, 64, 0, stream>>>(x, tgt, rep, coef, nout);
  gemm_logits_k<<<dim3(NCB, NRB), 256, 0, stream>>>(x, dec_w, dec_b, tgt, nout,
                                                    out, pmax, psum);
  combine_k<<<NROWS, 64, 0, stream>>>(pmax, psum, roff);

  const int total4 = (NROWS * NTOKEN) / 4;   // 112,575,680 / 4 — divisible
  normalize_k<<<(total4 + 255) / 256, 256, 0, stream>>>(out, roff, total4);
}